// Round 9
// baseline (394.031 us; speedup 1.0000x reference)
//
#include <hip/hip_runtime.h>

#define NPROT 12288
#define NMOL  6144
#define HID   256
#define NB    32

// bf16 scratch layout (u16-element offsets, base = ws + 1024)
#define MOL_O  3145728
#define WQ_O   4718592
#define WK_O   4784128
#define WV_O   4849664
#define BQ_O   4915200
#define BK_O   4915456
#define BV_O   4915712
#define Q_O    4915968
#define K_O    8061696
#define VT_O   9634560
#define END_O  11207424

// attn-region zero fill, split across all three kernels (8-row units):
//   convert: fids   0..639   (rows    0..5119)
//   proj:    fids 640..1023  (rows 5120..8191)
//   attn:    256 blocks x 16 rows (rows 8192..12287), skipping live cols
#define FROWS_BLK 49152            // floats per 8-row fill unit
#define CVT_BLKS  1729             // ceil(442560/256)
#define CVT_FILL  640
#define PROJ_BLKS 672              // 192 Q + 96 K + 384 V
#define PROJ_FILL 384

typedef __attribute__((ext_vector_type(4))) float f32x4;
typedef __attribute__((ext_vector_type(8))) short bf16x8;
typedef unsigned short u16;
typedef unsigned int   u32;

__device__ __forceinline__ float b2f(u16 u){
  union { u32 i; float f; } v; v.i = ((u32)u) << 16; return v.f;
}
__device__ __forceinline__ u16 f2b(float f){
  union { float fl; u32 i; } v; v.fl = f;
  u32 i = v.i;
  return (u16)((i + 0x7FFFu + ((i >> 16) & 1u)) >> 16);  // RNE
}

// zero 8 contiguous attn rows (fid in [0,1024))
__device__ __forceinline__ void fill_rows8(float* attnf, int fid){
  float* dst = attnf + (size_t)fid * FROWS_BLK + threadIdx.x * 4;
  f32x4 z = {0.f, 0.f, 0.f, 0.f};
  #pragma unroll 4
  for (int i = 0; i < 48; i++)
    __builtin_nontemporal_store(z, (f32x4*)(dst + i * 1024));
}

// ---------------------------------------------------------------------------
// Convert: f32 -> bf16 for mol + W + biases into ws (prot is consumed f32
// directly by proj). Block 0 wave 0 computes per-batch ranges via binary
// search. Blocks >= CVT_BLKS zero-fill attn rows 0..5119.
// ---------------------------------------------------------------------------
__global__ __launch_bounds__(256) void convert_kernel(
    const float* __restrict__ mol,
    const float* __restrict__ Wq, const float* __restrict__ Wk,
    const float* __restrict__ Wv, const float* __restrict__ bq,
    const float* __restrict__ bk, const float* __restrict__ bv,
    const int* __restrict__ pb, const int* __restrict__ mb,
    int* __restrict__ rg, u16* __restrict__ cvt, float* __restrict__ dout)
{
  if (blockIdx.x >= CVT_BLKS){
    fill_rows8(dout + (size_t)NPROT * HID, blockIdx.x - CVT_BLKS);
    return;
  }
  int g = blockIdx.x * 256 + threadIdx.x;   // quad index
  const float* src = nullptr; u16* dst = nullptr; int off = 0;
  if      (g < 393216) { src = mol; dst = cvt + MOL_O; off = g; }
  else if (g < 409600) { src = Wq;  dst = cvt + WQ_O;  off = g - 393216; }
  else if (g < 425984) { src = Wk;  dst = cvt + WK_O;  off = g - 409600; }
  else if (g < 442368) { src = Wv;  dst = cvt + WV_O;  off = g - 425984; }
  else if (g < 442432) { src = bq;  dst = cvt + BQ_O;  off = g - 442368; }
  else if (g < 442496) { src = bk;  dst = cvt + BK_O;  off = g - 442432; }
  else if (g < 442560) { src = bv;  dst = cvt + BV_O;  off = g - 442496; }
  if (src){
    f32x4 v = *(const f32x4*)(src + (size_t)off * 4);
    ushort4 o;
    o.x = f2b(v[0]); o.y = f2b(v[1]); o.z = f2b(v[2]); o.w = f2b(v[3]);
    *(ushort4*)(dst + (size_t)off * 4) = o;
  }

  if (blockIdx.x == 0 && threadIdx.x < 64){
    int t = threadIdx.x;
    const int* arr = (t < 32) ? pb : mb;
    int n          = (t < 32) ? NPROT : NMOL;
    int target     = (t & 31) + 1;
    int lo = 0, hi = n;
    while (lo < hi){                // lower_bound(target)
      int mid = (lo + hi) >> 1;
      if (arr[mid] < target) lo = mid + 1; else hi = mid;
    }
    int end = lo;
    int prev = __shfl(end, t - 1);  // end of batch b-1 == start of batch b
    int start = ((t & 31) == 0) ? 0 : prev;
    int b = t & 31;
    if (t < 32){ rg[b] = start; rg[32 + b] = end; }
    else       { rg[64 + b] = start; rg[96 + b] = end; }
  }
}

// ---------------------------------------------------------------------------
// Projections. 1-D grid:
//   x in [0,192)    : Q full-col tile (64 rows x 256 cols), prot read f32
//                     directly (NT) with in-register bf16 conversion (amortized
//                     over 16 MFMAs per k-step); X read exactly once.
//   x in [192,288)  : K full-col tile, mol bf16 from cvt (read once).
//   x in [288,672)  : V 64-col tiles + LDS transpose -> Vt[h][mol] (as before).
//   x >= 672        : zero-fill attn rows 5120..8191.
// C/D layout: col = lane&15, row = (lane>>4)*4 + reg.
// ---------------------------------------------------------------------------
__global__ __launch_bounds__(256) void proj_kernel(
    const float* __restrict__ prot, const u16* __restrict__ cvt,
    u16* __restrict__ Q, u16* __restrict__ K, u16* __restrict__ Vt,
    float* __restrict__ dout)
{
  __shared__ u16 tlds[4][64][18];
  int x = blockIdx.x;
  if (x >= PROJ_BLKS){
    fill_rows8(dout + (size_t)NPROT * HID, (x - PROJ_BLKS) + CVT_FILL);
    return;
  }
  int wave = threadIdx.x >> 6, lane = threadIdx.x & 63;
  int m = lane & 15, q = lane >> 4;

  if (x < 288){
    // ---- Q / K full-col path ----
    bool isQ = (x < 192);
    int rowbase = (isQ ? x : (x - 192)) * 64 + wave * 16;
    const u16* W = cvt + (isQ ? WQ_O : WK_O);
    const u16* B = cvt + (isQ ? BQ_O : BK_O);
    u16* O = isQ ? Q : K;

    f32x4 acc[16] = {};
    for (int k0 = 0; k0 < HID; k0 += 32){
      bf16x8 a;
      if (isQ){
        const float* ar = prot + (size_t)(rowbase + m) * HID + k0 + q*8;
        f32x4 v0 = __builtin_nontemporal_load((const f32x4*)ar);
        f32x4 v1 = __builtin_nontemporal_load((const f32x4*)(ar + 4));
        a[0]=(short)f2b(v0[0]); a[1]=(short)f2b(v0[1]);
        a[2]=(short)f2b(v0[2]); a[3]=(short)f2b(v0[3]);
        a[4]=(short)f2b(v1[0]); a[5]=(short)f2b(v1[1]);
        a[6]=(short)f2b(v1[2]); a[7]=(short)f2b(v1[3]);
      } else {
        a = *(const bf16x8*)(cvt + MOL_O + (size_t)(rowbase + m) * HID + k0 + q*8);
      }
      #pragma unroll
      for (int ct = 0; ct < 16; ct++){
        bf16x8 b = *(const bf16x8*)(W + (size_t)(ct*16 + m) * HID + k0 + q*8);
        acc[ct] = __builtin_amdgcn_mfma_f32_16x16x32_bf16(a, b, acc[ct], 0, 0, 0);
      }
    }
    #pragma unroll
    for (int ct = 0; ct < 16; ct++){
      int col = ct*16 + m;
      float bb = b2f(B[col]);
      #pragma unroll
      for (int r = 0; r < 4; r++){
        int row = rowbase + q*4 + r;
        O[(size_t)row * HID + col] = f2b(acc[ct][r] + bb);
      }
    }
    return;
  }

  // ---- V path: 64-col tiles + transpose ----
  int v = x - 288;
  int rowblk = v >> 2, colblk = v & 3;
  const u16* X = cvt + MOL_O;
  const u16* W = cvt + WV_O;
  const u16* B = cvt + BV_O;
  int rowbase = rowblk * 64 + wave * 16;
  int colbase = colblk * 64;

  const u16* arow = X + (size_t)(rowbase + m) * HID;
  f32x4 acc[4] = {};
  for (int k0 = 0; k0 < HID; k0 += 32){
    bf16x8 a = *(const bf16x8*)(arow + k0 + q*8);
    #pragma unroll
    for (int ct = 0; ct < 4; ct++){
      bf16x8 b = *(const bf16x8*)(W + (size_t)(colbase + ct*16 + m) * HID + k0 + q*8);
      acc[ct] = __builtin_amdgcn_mfma_f32_16x16x32_bf16(a, b, acc[ct], 0, 0, 0);
    }
  }
  #pragma unroll
  for (int ct = 0; ct < 4; ct++){
    int lc = ct*16 + m;
    float bb = b2f(B[colbase + lc]);
    #pragma unroll
    for (int r = 0; r < 4; r++)
      tlds[wave][lc][q*4 + r] = f2b(acc[ct][r] + bb);
  }
  __syncthreads();
  int col = colbase + lane;
  u32 packed[8];
  #pragma unroll
  for (int i = 0; i < 8; i++){
    u16 lo = tlds[wave][lane][2*i];
    u16 hi = tlds[wave][lane][2*i+1];
    packed[i] = (u32)lo | ((u32)hi << 16);
  }
  u16* dst = Vt + (size_t)col * NMOL + rowbase;
  uint4 v0 = {packed[0], packed[1], packed[2], packed[3]};
  uint4 v1 = {packed[4], packed[5], packed[6], packed[7]};
  *(uint4*)dst = v0;
  *(uint4*)(dst + 8) = v1;
}

// ---------------------------------------------------------------------------
// Attention (f32 out). grid (40, 32): x<32 -> compute blocks for batch y;
// x>=32 -> fill blocks zeroing rows 8192..12287 (16 rows each), skipping
// each row's live cols [ms,me) (disjoint from the P stores -> no race).
// Compute: single QK^T, scores in registers:
//   A: S = QK^T (strip, regs) + row max      -> merge max via LDS
//   B: e = exp(s-gmx) (regs) + partial sums  -> merge sums via LDS
//   C: p = e*ginv -> attn global (NT) + P LDS (bf16)
//   D: PV with waves splitting HID (4 MFMA cols each) -> no O reduction
// ---------------------------------------------------------------------------
__global__ __launch_bounds__(256) void attn_kernel(
    const int* __restrict__ rg, const int* __restrict__ pb,
    const u16* __restrict__ Q, const u16* __restrict__ K,
    const u16* __restrict__ Vt, float* __restrict__ dout)
{
  __shared__ u16 P[16][392];        // P tile bf16, cols [bs,ce), pad->392
  __shared__ float mxw[4][16];
  __shared__ float smw[4][16];
  const float scale = 0.0625f;      // 1/sqrt(256)
  float* outf  = dout;
  float* attnf = dout + (size_t)NPROT * HID;

  if (blockIdx.x >= 32){
    // ---- fill block: 16 rows starting at 8192 + fid*16 ----
    int fid = (blockIdx.x - 32) + 8 * blockIdx.y;   // [0,256)
    int r0 = 8192 + fid * 16;
    f32x4 z = {0.f, 0.f, 0.f, 0.f};
    for (int rr = 0; rr < 16; rr++){
      int row = r0 + rr;
      int bb = pb[row];
      int ms = rg[64 + bb], me = rg[96 + bb];
      float* rowp = attnf + (size_t)row * NMOL;
      int mv = ms & ~3;
      for (int c = threadIdx.x * 4; c < mv; c += 1024)
        __builtin_nontemporal_store(z, (f32x4*)(rowp + c));
      for (int c = mv + threadIdx.x; c < ms; c += 256)
        rowp[c] = 0.f;
      int mu = (me + 3) & ~3;
      for (int c = me + threadIdx.x; c < mu && c < NMOL; c += 256)
        rowp[c] = 0.f;
      for (int c = mu + threadIdx.x * 4; c < NMOL; c += 1024)
        __builtin_nontemporal_store(z, (f32x4*)(rowp + c));
    }
    return;
  }

  int b = blockIdx.y;
  int ps = rg[b], pe = rg[32+b], ms = rg[64+b], me = rg[96+b];
  int Np = pe - ps, Nm = me - ms;
  if (Np <= 0) return;

  int wave = threadIdx.x >> 6, lane = threadIdx.x & 63;
  int m = lane & 15, q = lane >> 4;
  int ntiles = (Np + 15) >> 4;

  int bs = 0, ce = 0;
  if (Nm > 0){ bs = ms & ~31; ce = bs + ((me - bs + 31) & ~31); }  // ce <= NMOL

  for (int tile = blockIdx.x; tile < ntiles; tile += 32){
    int row0 = ps + tile * 16;
    int qr = min(row0 + m, NPROT - 1);
    const u16* qrow = Q + (size_t)qr * HID;
    bf16x8 qf[8];
    #pragma unroll
    for (int kk = 0; kk < 8; kk++)
      qf[kk] = *(const bf16x8*)(qrow + kk*32 + q*8);

    if (Nm > 0){
      int myj0 = bs + wave * 16;
      // ---- phase A: single QK^T pass, scores -> registers, track max ----
      f32x4 sreg[6];
      float mx[4] = {-1e30f, -1e30f, -1e30f, -1e30f};
      #pragma unroll
      for (int c = 0; c < 6; c++){
        int j0 = myj0 + 64*c;
        if (j0 < ce){
          int col = j0 + m;                         // col <= ce-1 < NMOL
          bool valid = (col >= ms) && (col < me);
          const u16* krow = K + (size_t)col * HID;
          f32x4 s0 = {0.f,0.f,0.f,0.f}, s1 = {0.f,0.f,0.f,0.f};
          #pragma unroll
          for (int kk = 0; kk < 4; kk++){
            bf16x8 kb0 = *(const bf16x8*)(krow + kk*32 + q*8);
            bf16x8 kb1 = *(const bf16x8*)(krow + (kk+4)*32 + q*8);
            s0 = __builtin_amdgcn_mfma_f32_16x16x32_bf16(qf[kk],   kb0, s0, 0, 0, 0);
            s1 = __builtin_amdgcn_mfma_f32_16x16x32_bf16(qf[kk+4], kb1, s1, 0, 0, 0);
          }
          f32x4 sv;
          #pragma unroll
          for (int r = 0; r < 4; r++)
            sv[r] = valid ? (s0[r] + s1[r]) * scale : -1e30f;
          sreg[c] = sv;
          float cm[4];
          #pragma unroll
          for (int r = 0; r < 4; r++) cm[r] = sv[r];
          #pragma unroll
          for (int d = 1; d < 16; d <<= 1)
            #pragma unroll
            for (int r = 0; r < 4; r++)
              cm[r] = fmaxf(cm[r], __shfl_xor(cm[r], d, 16));
          #pragma unroll
          for (int r = 0; r < 4; r++) mx[r] = fmaxf(mx[r], cm[r]);
        }
      }
      if (m == 0){
        #pragma unroll
        for (int r = 0; r < 4; r++) mxw[wave][q*4 + r] = mx[r];
      }
      __syncthreads();
      float gmx[4];
      #pragma unroll
      for (int r = 0; r < 4; r++){
        int row = q*4 + r;
        float M = mxw[0][row];
        #pragma unroll
        for (int w = 1; w < 4; w++) M = fmaxf(M, mxw[w][row]);
        gmx[r] = M;
      }

      // ---- phase B: exponentiate in regs + partial row sums ----
      float sm[4] = {0.f, 0.f, 0.f, 0.f};
      #pragma unroll
      for (int c = 0; c < 6; c++){
        int j0 = myj0 + 64*c;
        if (j0 < ce){
          f32x4 e;
          #pragma unroll
          for (int r = 0; r < 4; r++) e[r] = __expf(sreg[c][r] - gmx[r]);
          sreg[c] = e;
          float t[4];
          #pragma unroll
          for (int r = 0; r < 4; r++) t[r] = e[r];
          #pragma unroll
          for (int d = 1; d < 16; d <<= 1)
            #pragma unroll
            for (int r = 0; r < 4; r++)
              t[r] += __shfl_xor(t[r], d, 16);
          #pragma unroll
          for (int r = 0; r < 4; r++) sm[r] += t[r];
        }
      }
      if (m == 0){
        #pragma unroll
        for (int r = 0; r < 4; r++) smw[wave][q*4 + r] = sm[r];
      }
      __syncthreads();
      float ginv[4];
      #pragma unroll
      for (int r = 0; r < 4; r++){
        int row = q*4 + r;
        float S = smw[0][row] + smw[1][row] + smw[2][row] + smw[3][row];
        ginv[r] = (S > 0.f) ? (1.f / S) : 0.f;
      }

      // ---- phase C: normalize -> attn global + P LDS ----
      #pragma unroll
      for (int c = 0; c < 6; c++){
        int j0 = myj0 + 64*c;
        if (j0 < ce){
          int col = j0 + m;
          int jl = j0 - bs;
          bool valid = (col >= ms) && (col < me);
          #pragma unroll
          for (int r = 0; r < 4; r++){
            float p = sreg[c][r] * ginv[r];
            P[q*4 + r][jl + m] = f2b(p);
            int row = row0 + q*4 + r;
            if (valid && row < pe)
              __builtin_nontemporal_store(p, attnf + (size_t)row * NMOL + col);
          }
        }
      }
      __syncthreads();

      // ---- phase D: PV, waves split HID (ct = wave*4 .. wave*4+3) ----
      f32x4 oacc[4] = {};
      for (int j0 = bs; j0 < ce; j0 += 32){
        int jl = j0 - bs;
        bf16x8 a = *(const bf16x8*)(&P[m][jl + q*8]);
        #pragma unroll
        for (int c2 = 0; c2 < 4; c2++){
          int ct = wave*4 + c2;
          bf16x8 vb = *(const bf16x8*)(Vt + (size_t)(ct*16 + m) * NMOL + j0 + q*8);
          oacc[c2] = __builtin_amdgcn_mfma_f32_16x16x32_bf16(a, vb, oacc[c2], 0, 0, 0);
        }
      }
      #pragma unroll
      for (int c2 = 0; c2 < 4; c2++){
        int col = (wave*4 + c2)*16 + m;
        #pragma unroll
        for (int r = 0; r < 4; r++){
          int row = row0 + q*4 + r;
          if (row < pe) outf[(size_t)row * HID + col] = oacc[c2][r];
        }
      }
    } else {
      // no valid keys: O rows are zeros (waves split HID)
      #pragma unroll
      for (int c2 = 0; c2 < 4; c2++){
        int col = (wave*4 + c2)*16 + m;
        #pragma unroll
        for (int r = 0; r < 4; r++){
          int row = row0 + q*4 + r;
          if (row < pe) outf[(size_t)row * HID + col] = 0.f;
        }
      }
    }
    __syncthreads();   // protect P/mxw/smw reuse across tile iterations
  }
}

extern "C" void kernel_launch(void* const* d_in, const int* in_sizes, int n_in,
                              void* d_out, int out_size, void* d_ws, size_t ws_size,
                              hipStream_t stream)
{
  (void)in_sizes; (void)n_in; (void)out_size;
  const float* prot = (const float*)d_in[0];
  const float* mol  = (const float*)d_in[1];
  const int* pb     = (const int*)d_in[2];
  const int* mb     = (const int*)d_in[3];
  const float* Wq   = (const float*)d_in[4];
  const float* bq   = (const float*)d_in[5];
  const float* Wk   = (const float*)d_in[6];
  const float* bk   = (const float*)d_in[7];
  const float* Wv   = (const float*)d_in[8];
  const float* bv   = (const float*)d_in[9];

  const size_t need = 1024 + (size_t)END_O * 2;
  if (ws_size < need) return;

  char* ws = (char*)d_ws;
  int* rg  = (int*)ws;
  u16* cvt = (u16*)(ws + 1024);
  u16* Qp  = cvt + Q_O;
  u16* Kp  = cvt + K_O;
  u16* Vtp = cvt + VT_O;
  float* out = (float*)d_out;

  convert_kernel<<<dim3(CVT_BLKS + CVT_FILL), dim3(256), 0, stream>>>(
      mol, Wq, Wk, Wv, bq, bk, bv, pb, mb, rg, cvt, out);
  proj_kernel<<<dim3(PROJ_BLKS + PROJ_FILL), dim3(256), 0, stream>>>(
      prot, cvt, Qp, Kp, Vtp, out);
  attn_kernel<<<dim3(40, NB), dim3(256), 0, stream>>>(rg, pb, Qp, Kp, Vtp, out);
}

// Round 10
// 390.684 us; speedup vs baseline: 1.0086x; 1.0086x over previous
//
#include <hip/hip_runtime.h>

#define NPROT 12288
#define NMOL  6144
#define HID   256
#define NB    32

// bf16 scratch layout (u16-element offsets, base = ws + 1024)
#define WQ_O   4718592
#define WK_O   4784128
#define WV_O   4849664
#define BQ_O   4915200
#define BK_O   4915456
#define BV_O   4915712
#define Q_O    4915968
#define K_O    8061696
#define VT_O   9634560
#define END_O  11207424

// attn-region zero fill split:
//   convert: 512 x 8-row full units   (rows    0..4095)
//   proj:    256 x 16-row masked      (rows 4096..8191)
//   attn:    256 x 16-row masked      (rows 8192..12287)
#define FROWS_BLK 49152            // floats per 8-row fill unit
#define CVT_BLKS  193              // ceil(49344/256): W + biases only
#define CVT_FILL  512
#define PROJ_BLKS 672              // 192 Q + 96 K + 384 V
#define PROJ_FILL 256

typedef __attribute__((ext_vector_type(4))) float f32x4;
typedef __attribute__((ext_vector_type(8))) short bf16x8;
typedef unsigned short u16;
typedef unsigned int   u32;

__device__ __forceinline__ float b2f(u16 u){
  union { u32 i; float f; } v; v.i = ((u32)u) << 16; return v.f;
}
__device__ __forceinline__ u16 f2b(float f){
  union { float fl; u32 i; } v; v.fl = f;
  u32 i = v.i;
  return (u16)((i + 0x7FFFu + ((i >> 16) & 1u)) >> 16);  // RNE
}

// convert two f32x4 to one bf16x8 fragment
__device__ __forceinline__ bf16x8 cvt8(f32x4 v0, f32x4 v1){
  bf16x8 a;
  a[0]=(short)f2b(v0[0]); a[1]=(short)f2b(v0[1]);
  a[2]=(short)f2b(v0[2]); a[3]=(short)f2b(v0[3]);
  a[4]=(short)f2b(v1[0]); a[5]=(short)f2b(v1[1]);
  a[6]=(short)f2b(v1[2]); a[7]=(short)f2b(v1[3]);
  return a;
}

// zero 8 contiguous attn rows (fid in [0,512))
__device__ __forceinline__ void fill_rows8(float* attnf, int fid){
  float* dst = attnf + (size_t)fid * FROWS_BLK + threadIdx.x * 4;
  f32x4 z = {0.f, 0.f, 0.f, 0.f};
  #pragma unroll 4
  for (int i = 0; i < 48; i++)
    __builtin_nontemporal_store(z, (f32x4*)(dst + i * 1024));
}

// zero 16 attn rows starting at r0, skipping each row's live cols [ms,me)
__device__ __forceinline__ void fill_rows16_masked(
    float* attnf, const int* pb, const int* rg, int r0){
  f32x4 z = {0.f, 0.f, 0.f, 0.f};
  for (int rr = 0; rr < 16; rr++){
    int row = r0 + rr;
    int bb = pb[row];
    int ms = rg[64 + bb], me = rg[96 + bb];
    float* rowp = attnf + (size_t)row * NMOL;
    int mv = ms & ~3;
    for (int c = threadIdx.x * 4; c < mv; c += 1024)
      __builtin_nontemporal_store(z, (f32x4*)(rowp + c));
    for (int c = mv + threadIdx.x; c < ms; c += 256)
      rowp[c] = 0.f;
    int mu = (me + 3) & ~3;
    for (int c = me + threadIdx.x; c < mu && c < NMOL; c += 256)
      rowp[c] = 0.f;
    for (int c = mu + threadIdx.x * 4; c < NMOL; c += 1024)
      __builtin_nontemporal_store(z, (f32x4*)(rowp + c));
  }
}

// ---------------------------------------------------------------------------
// Convert: f32 -> bf16 for W + biases only (prot/mol consumed f32 directly by
// proj). Block 0 wave 0 computes per-batch ranges via binary search.
// Blocks >= CVT_BLKS zero-fill attn rows 0..4095.
// ---------------------------------------------------------------------------
__global__ __launch_bounds__(256) void convert_kernel(
    const float* __restrict__ Wq, const float* __restrict__ Wk,
    const float* __restrict__ Wv, const float* __restrict__ bq,
    const float* __restrict__ bk, const float* __restrict__ bv,
    const int* __restrict__ pb, const int* __restrict__ mb,
    int* __restrict__ rg, u16* __restrict__ cvt, float* __restrict__ dout)
{
  if (blockIdx.x >= CVT_BLKS){
    fill_rows8(dout + (size_t)NPROT * HID, blockIdx.x - CVT_BLKS);
    return;
  }
  int g = blockIdx.x * 256 + threadIdx.x;   // quad index
  const float* src = nullptr; u16* dst = nullptr; int off = 0;
  if      (g < 16384) { src = Wq; dst = cvt + WQ_O; off = g; }
  else if (g < 32768) { src = Wk; dst = cvt + WK_O; off = g - 16384; }
  else if (g < 49152) { src = Wv; dst = cvt + WV_O; off = g - 32768; }
  else if (g < 49216) { src = bq; dst = cvt + BQ_O; off = g - 49152; }
  else if (g < 49280) { src = bk; dst = cvt + BK_O; off = g - 49216; }
  else if (g < 49344) { src = bv; dst = cvt + BV_O; off = g - 49280; }
  if (src){
    f32x4 v = *(const f32x4*)(src + (size_t)off * 4);
    ushort4 o;
    o.x = f2b(v[0]); o.y = f2b(v[1]); o.z = f2b(v[2]); o.w = f2b(v[3]);
    *(ushort4*)(dst + (size_t)off * 4) = o;
  }

  if (blockIdx.x == 0 && threadIdx.x < 64){
    int t = threadIdx.x;
    const int* arr = (t < 32) ? pb : mb;
    int n          = (t < 32) ? NPROT : NMOL;
    int target     = (t & 31) + 1;
    int lo = 0, hi = n;
    while (lo < hi){                // lower_bound(target)
      int mid = (lo + hi) >> 1;
      if (arr[mid] < target) lo = mid + 1; else hi = mid;
    }
    int end = lo;
    int prev = __shfl(end, t - 1);  // end of batch b-1 == start of batch b
    int start = ((t & 31) == 0) ? 0 : prev;
    int b = t & 31;
    if (t < 32){ rg[b] = start; rg[32 + b] = end; }
    else       { rg[64 + b] = start; rg[96 + b] = end; }
  }
}

// ---------------------------------------------------------------------------
// Projections. 1-D grid:
//   x in [0,192)    : Q full-col tile, prot f32 NT + in-register bf16 cvt.
//   x in [192,288)  : K full-col tile, mol f32 (cached loads; V re-reads it).
//   x in [288,672)  : V 64-col tiles, mol f32 (L3-served re-reads) + LDS
//                     transpose -> Vt[h][mol].
//   x >= 672        : masked zero-fill of attn rows 4096..8191.
// W/biases bf16 from cvt. C/D layout: col=lane&15, row=(lane>>4)*4+reg.
// ---------------------------------------------------------------------------
__global__ __launch_bounds__(256) void proj_kernel(
    const float* __restrict__ prot, const float* __restrict__ mol,
    const u16* __restrict__ cvt, const int* __restrict__ rg,
    const int* __restrict__ pb,
    u16* __restrict__ Q, u16* __restrict__ K, u16* __restrict__ Vt,
    float* __restrict__ dout)
{
  __shared__ u16 tlds[4][64][18];
  int x = blockIdx.x;
  if (x >= PROJ_BLKS){
    fill_rows16_masked(dout + (size_t)NPROT * HID, pb, rg,
                       4096 + (x - PROJ_BLKS) * 16);
    return;
  }
  int wave = threadIdx.x >> 6, lane = threadIdx.x & 63;
  int m = lane & 15, q = lane >> 4;

  if (x < 288){
    // ---- Q / K full-col path ----
    bool isQ = (x < 192);
    int rowbase = (isQ ? x : (x - 192)) * 64 + wave * 16;
    const u16* W = cvt + (isQ ? WQ_O : WK_O);
    const u16* B = cvt + (isQ ? BQ_O : BK_O);
    u16* O = isQ ? Q : K;
    const float* X = isQ ? prot : mol;

    f32x4 acc[16] = {};
    for (int k0 = 0; k0 < HID; k0 += 32){
      const float* ar = X + (size_t)(rowbase + m) * HID + k0 + q*8;
      f32x4 v0, v1;
      if (isQ){
        v0 = __builtin_nontemporal_load((const f32x4*)ar);
        v1 = __builtin_nontemporal_load((const f32x4*)(ar + 4));
      } else {
        v0 = *(const f32x4*)ar;
        v1 = *(const f32x4*)(ar + 4);
      }
      bf16x8 a = cvt8(v0, v1);
      #pragma unroll
      for (int ct = 0; ct < 16; ct++){
        bf16x8 b = *(const bf16x8*)(W + (size_t)(ct*16 + m) * HID + k0 + q*8);
        acc[ct] = __builtin_amdgcn_mfma_f32_16x16x32_bf16(a, b, acc[ct], 0, 0, 0);
      }
    }
    #pragma unroll
    for (int ct = 0; ct < 16; ct++){
      int col = ct*16 + m;
      float bb = b2f(B[col]);
      #pragma unroll
      for (int r = 0; r < 4; r++){
        int row = rowbase + q*4 + r;
        O[(size_t)row * HID + col] = f2b(acc[ct][r] + bb);
      }
    }
    return;
  }

  // ---- V path: 64-col tiles + transpose (mol f32, L3-served re-reads) ----
  int v = x - 288;
  int rowblk = v >> 2, colblk = v & 3;
  const u16* W = cvt + WV_O;
  const u16* B = cvt + BV_O;
  int rowbase = rowblk * 64 + wave * 16;
  int colbase = colblk * 64;

  const float* arow = mol + (size_t)(rowbase + m) * HID;
  f32x4 acc[4] = {};
  for (int k0 = 0; k0 < HID; k0 += 32){
    f32x4 v0 = *(const f32x4*)(arow + k0 + q*8);
    f32x4 v1 = *(const f32x4*)(arow + k0 + q*8 + 4);
    bf16x8 a = cvt8(v0, v1);
    #pragma unroll
    for (int ct = 0; ct < 4; ct++){
      bf16x8 b = *(const bf16x8*)(W + (size_t)(colbase + ct*16 + m) * HID + k0 + q*8);
      acc[ct] = __builtin_amdgcn_mfma_f32_16x16x32_bf16(a, b, acc[ct], 0, 0, 0);
    }
  }
  #pragma unroll
  for (int ct = 0; ct < 4; ct++){
    int lc = ct*16 + m;
    float bb = b2f(B[colbase + lc]);
    #pragma unroll
    for (int r = 0; r < 4; r++)
      tlds[wave][lc][q*4 + r] = f2b(acc[ct][r] + bb);
  }
  __syncthreads();
  int col = colbase + lane;
  u32 packed[8];
  #pragma unroll
  for (int i = 0; i < 8; i++){
    u16 lo = tlds[wave][lane][2*i];
    u16 hi = tlds[wave][lane][2*i+1];
    packed[i] = (u32)lo | ((u32)hi << 16);
  }
  u16* dst = Vt + (size_t)col * NMOL + rowbase;
  uint4 v0 = {packed[0], packed[1], packed[2], packed[3]};
  uint4 v1 = {packed[4], packed[5], packed[6], packed[7]};
  *(uint4*)dst = v0;
  *(uint4*)(dst + 8) = v1;
}

// ---------------------------------------------------------------------------
// Attention (f32 out). grid (40, 32): x<32 -> compute blocks for batch y;
// x>=32 -> masked fill of rows 8192..12287 (16 rows each).
// Compute: single QK^T, scores in registers:
//   A: S = QK^T (strip, regs) + row max      -> merge max via LDS
//   B: e = exp(s-gmx) (regs) + partial sums  -> merge sums via LDS
//   C: p = e*ginv -> attn global (NT) + P LDS (bf16)
//   D: PV with waves splitting HID (4 MFMA cols each) -> no O reduction
// ---------------------------------------------------------------------------
__global__ __launch_bounds__(256) void attn_kernel(
    const int* __restrict__ rg, const int* __restrict__ pb,
    const u16* __restrict__ Q, const u16* __restrict__ K,
    const u16* __restrict__ Vt, float* __restrict__ dout)
{
  __shared__ u16 P[16][392];        // P tile bf16, cols [bs,ce), pad->392
  __shared__ float mxw[4][16];
  __shared__ float smw[4][16];
  const float scale = 0.0625f;      // 1/sqrt(256)
  float* outf  = dout;
  float* attnf = dout + (size_t)NPROT * HID;

  if (blockIdx.x >= 32){
    int fid = (blockIdx.x - 32) + 8 * blockIdx.y;   // [0,256)
    fill_rows16_masked(attnf, pb, rg, 8192 + fid * 16);
    return;
  }

  int b = blockIdx.y;
  int ps = rg[b], pe = rg[32+b], ms = rg[64+b], me = rg[96+b];
  int Np = pe - ps, Nm = me - ms;
  if (Np <= 0) return;

  int wave = threadIdx.x >> 6, lane = threadIdx.x & 63;
  int m = lane & 15, q = lane >> 4;
  int ntiles = (Np + 15) >> 4;

  int bs = 0, ce = 0;
  if (Nm > 0){ bs = ms & ~31; ce = bs + ((me - bs + 31) & ~31); }  // ce <= NMOL

  for (int tile = blockIdx.x; tile < ntiles; tile += 32){
    int row0 = ps + tile * 16;
    int qr = min(row0 + m, NPROT - 1);
    const u16* qrow = Q + (size_t)qr * HID;
    bf16x8 qf[8];
    #pragma unroll
    for (int kk = 0; kk < 8; kk++)
      qf[kk] = *(const bf16x8*)(qrow + kk*32 + q*8);

    if (Nm > 0){
      int myj0 = bs + wave * 16;
      // ---- phase A: single QK^T pass, scores -> registers, track max ----
      f32x4 sreg[6];
      float mx[4] = {-1e30f, -1e30f, -1e30f, -1e30f};
      #pragma unroll
      for (int c = 0; c < 6; c++){
        int j0 = myj0 + 64*c;
        if (j0 < ce){
          int col = j0 + m;                         // col <= ce-1 < NMOL
          bool valid = (col >= ms) && (col < me);
          const u16* krow = K + (size_t)col * HID;
          f32x4 s0 = {0.f,0.f,0.f,0.f}, s1 = {0.f,0.f,0.f,0.f};
          #pragma unroll
          for (int kk = 0; kk < 4; kk++){
            bf16x8 kb0 = *(const bf16x8*)(krow + kk*32 + q*8);
            bf16x8 kb1 = *(const bf16x8*)(krow + (kk+4)*32 + q*8);
            s0 = __builtin_amdgcn_mfma_f32_16x16x32_bf16(qf[kk],   kb0, s0, 0, 0, 0);
            s1 = __builtin_amdgcn_mfma_f32_16x16x32_bf16(qf[kk+4], kb1, s1, 0, 0, 0);
          }
          f32x4 sv;
          #pragma unroll
          for (int r = 0; r < 4; r++)
            sv[r] = valid ? (s0[r] + s1[r]) * scale : -1e30f;
          sreg[c] = sv;
          float cm[4];
          #pragma unroll
          for (int r = 0; r < 4; r++) cm[r] = sv[r];
          #pragma unroll
          for (int d = 1; d < 16; d <<= 1)
            #pragma unroll
            for (int r = 0; r < 4; r++)
              cm[r] = fmaxf(cm[r], __shfl_xor(cm[r], d, 16));
          #pragma unroll
          for (int r = 0; r < 4; r++) mx[r] = fmaxf(mx[r], cm[r]);
        }
      }
      if (m == 0){
        #pragma unroll
        for (int r = 0; r < 4; r++) mxw[wave][q*4 + r] = mx[r];
      }
      __syncthreads();
      float gmx[4];
      #pragma unroll
      for (int r = 0; r < 4; r++){
        int row = q*4 + r;
        float M = mxw[0][row];
        #pragma unroll
        for (int w = 1; w < 4; w++) M = fmaxf(M, mxw[w][row]);
        gmx[r] = M;
      }

      // ---- phase B: exponentiate in regs + partial row sums ----
      float sm[4] = {0.f, 0.f, 0.f, 0.f};
      #pragma unroll
      for (int c = 0; c < 6; c++){
        int j0 = myj0 + 64*c;
        if (j0 < ce){
          f32x4 e;
          #pragma unroll
          for (int r = 0; r < 4; r++) e[r] = __expf(sreg[c][r] - gmx[r]);
          sreg[c] = e;
          float t[4];
          #pragma unroll
          for (int r = 0; r < 4; r++) t[r] = e[r];
          #pragma unroll
          for (int d = 1; d < 16; d <<= 1)
            #pragma unroll
            for (int r = 0; r < 4; r++)
              t[r] += __shfl_xor(t[r], d, 16);
          #pragma unroll
          for (int r = 0; r < 4; r++) sm[r] += t[r];
        }
      }
      if (m == 0){
        #pragma unroll
        for (int r = 0; r < 4; r++) smw[wave][q*4 + r] = sm[r];
      }
      __syncthreads();
      float ginv[4];
      #pragma unroll
      for (int r = 0; r < 4; r++){
        int row = q*4 + r;
        float S = smw[0][row] + smw[1][row] + smw[2][row] + smw[3][row];
        ginv[r] = (S > 0.f) ? (1.f / S) : 0.f;
      }

      // ---- phase C: normalize -> attn global + P LDS ----
      #pragma unroll
      for (int c = 0; c < 6; c++){
        int j0 = myj0 + 64*c;
        if (j0 < ce){
          int col = j0 + m;
          int jl = j0 - bs;
          bool valid = (col >= ms) && (col < me);
          #pragma unroll
          for (int r = 0; r < 4; r++){
            float p = sreg[c][r] * ginv[r];
            P[q*4 + r][jl + m] = f2b(p);
            int row = row0 + q*4 + r;
            if (valid && row < pe)
              __builtin_nontemporal_store(p, attnf + (size_t)row * NMOL + col);
          }
        }
      }
      __syncthreads();

      // ---- phase D: PV, waves split HID (ct = wave*4 .. wave*4+3) ----
      f32x4 oacc[4] = {};
      for (int j0 = bs; j0 < ce; j0 += 32){
        int jl = j0 - bs;
        bf16x8 a = *(const bf16x8*)(&P[m][jl + q*8]);
        #pragma unroll
        for (int c2 = 0; c2 < 4; c2++){
          int ct = wave*4 + c2;
          bf16x8 vb = *(const bf16x8*)(Vt + (size_t)(ct*16 + m) * NMOL + j0 + q*8);
          oacc[c2] = __builtin_amdgcn_mfma_f32_16x16x32_bf16(a, vb, oacc[c2], 0, 0, 0);
        }
      }
      #pragma unroll
      for (int c2 = 0; c2 < 4; c2++){
        int col = (wave*4 + c2)*16 + m;
        #pragma unroll
        for (int r = 0; r < 4; r++){
          int row = row0 + q*4 + r;
          if (row < pe) outf[(size_t)row * HID + col] = oacc[c2][r];
        }
      }
    } else {
      // no valid keys: O rows are zeros (waves split HID)
      #pragma unroll
      for (int c2 = 0; c2 < 4; c2++){
        int col = (wave*4 + c2)*16 + m;
        #pragma unroll
        for (int r = 0; r < 4; r++){
          int row = row0 + q*4 + r;
          if (row < pe) outf[(size_t)row * HID + col] = 0.f;
        }
      }
    }
    __syncthreads();   // protect P/mxw/smw reuse across tile iterations
  }
}

extern "C" void kernel_launch(void* const* d_in, const int* in_sizes, int n_in,
                              void* d_out, int out_size, void* d_ws, size_t ws_size,
                              hipStream_t stream)
{
  (void)in_sizes; (void)n_in; (void)out_size;
  const float* prot = (const float*)d_in[0];
  const float* mol  = (const float*)d_in[1];
  const int* pb     = (const int*)d_in[2];
  const int* mb     = (const int*)d_in[3];
  const float* Wq   = (const float*)d_in[4];
  const float* bq   = (const float*)d_in[5];
  const float* Wk   = (const float*)d_in[6];
  const float* bk   = (const float*)d_in[7];
  const float* Wv   = (const float*)d_in[8];
  const float* bv   = (const float*)d_in[9];

  const size_t need = 1024 + (size_t)END_O * 2;
  if (ws_size < need) return;

  char* ws = (char*)d_ws;
  int* rg  = (int*)ws;
  u16* cvt = (u16*)(ws + 1024);
  u16* Qp  = cvt + Q_O;
  u16* Kp  = cvt + K_O;
  u16* Vtp = cvt + VT_O;
  float* out = (float*)d_out;

  convert_kernel<<<dim3(CVT_BLKS + CVT_FILL), dim3(256), 0, stream>>>(
      Wq, Wk, Wv, bq, bk, bv, pb, mb, rg, cvt, out);
  proj_kernel<<<dim3(PROJ_BLKS + PROJ_FILL), dim3(256), 0, stream>>>(
      prot, mol, cvt, rg, pb, Qp, Kp, Vtp, out);
  attn_kernel<<<dim3(40, NB), dim3(256), 0, stream>>>(rg, pb, Qp, Kp, Vtp, out);
}